// Round 14
// baseline (97.796 us; speedup 1.0000x reference)
//
#include <hip/hip_runtime.h>
#include <math.h>

// MidpointMLR: B=1048576, F=64, c=1. Single fused kernel, 4 MFMA steps/wave.
// out = proj( sinh( 2*z_norm * asinh( (2*(x@zu)*cosh(2b) - (1+cx2)*sinh(2b)) / max(1-cx2,eps) ) ) )

#define MLR_B 1048576

typedef __bf16 bf16x8 __attribute__((ext_vector_type(8)));
typedef __bf16 bf16x4 __attribute__((ext_vector_type(4)));
typedef float  f32x4  __attribute__((ext_vector_type(4)));

#define LOG2E 1.4426950408889634f

// y = sinh( g * asinh(t) ) via exp2/log2 — sign-transparent: u = t+sqrt(1+t^2) > 0.
// NB: __builtin_amdgcn_logf IS v_log_f32 = log2.
__device__ __forceinline__ float poin_y(float dot, float ch2, float sh, float g,
                                        float opc, float rden) {
    float t = fmaf(dot, ch2, -(opc * sh)) * rden;
    float u = t + sqrtf(fmaf(t, t, 1.f));
    float w = __builtin_amdgcn_exp2f(g * __builtin_amdgcn_logf(u));   // u^g
    return 0.5f * (w - __builtin_amdgcn_rcpf(w));
}

struct StepMid {
    f32x4 acc[4];
    float p;        // cx2 for row lo
};

struct XQuad { f32x4 a, b, c, d; };

__device__ __forceinline__ XQuad loadx(const char* p) {
    XQuad q;
    q.a = *(const f32x4*)(p + 0);
    q.b = *(const f32x4*)(p + 64);
    q.c = *(const f32x4*)(p + 128);
    q.d = *(const f32x4*)(p + 192);
    return q;
}

// gemm phase: cx2 + bf16 pack + 8 MFMA. x regs die here.
__device__ __forceinline__ StepMid mlr_gemm(const XQuad& q, const bf16x8* bfr) {
    f32x4 c0 = q.a, c1 = q.b, c2 = q.c, c3 = q.d;
    StepMid m;
    float p = 0.f;
#pragma unroll
    for (int j = 0; j < 4; ++j) {
        p = fmaf(c0[j], c0[j], p); p = fmaf(c1[j], c1[j], p);
        p = fmaf(c2[j], c2[j], p); p = fmaf(c3[j], c3[j], p);
    }
    p += __shfl_xor(p, 16);
    p += __shfl_xor(p, 32);
    m.p = p;

    bf16x8 a0, a1;
#pragma unroll
    for (int j = 0; j < 4; ++j) {
        a0[j]     = (__bf16)c0[j];
        a0[4 + j] = (__bf16)c1[j];
        a1[j]     = (__bf16)c2[j];
        a1[4 + j] = (__bf16)c3[j];
    }

#pragma unroll
    for (int t = 0; t < 4; ++t) {
        m.acc[t] = (f32x4){0.f, 0.f, 0.f, 0.f};
        m.acc[t] = __builtin_amdgcn_mfma_f32_16x16x32_bf16(a0, bfr[t],     m.acc[t], 0, 0, 0);
        m.acc[t] = __builtin_amdgcn_mfma_f32_16x16x32_bf16(a1, bfr[4 + t], m.acc[t], 0, 0, 0);
    }
    return m;
}

// finish phase: transcendental epilogue + projection + nt stores.
// C/D map col=lo, row=4*hi+reg; acc[t][r] = physical col 4*lo+t.
__device__ __forceinline__ void mlr_fin(const StepMid& m, const f32x4* cc,
                                        int lo, int hi, char* ob) {
    f32x4 yv[4]; float S[4];
#pragma unroll
    for (int r = 0; r < 4; ++r) {
        float cxr  = __shfl(m.p, hi * 4 + r);          // cx2 of row 4*hi+r
        float opc  = 1.f + cxr;
        float rden = __builtin_amdgcn_rcpf(fmaxf(1.f - cxr, 1e-15f));
        float s0 = 0.f;
        f32x4 y;
#pragma unroll
        for (int t = 0; t < 4; ++t) {
            float v = poin_y(m.acc[t][r], cc[t].x, cc[t].y, cc[t].z, opc, rden);
            y[t] = v;
            s0 = fmaf(v, v, s0);
        }
        yv[r] = y;
        S[r] = s0;
    }
#pragma unroll
    for (int r = 0; r < 4; ++r) {
        float s0 = S[r];
        s0 += __shfl_xor(s0, 1);
        s0 += __shfl_xor(s0, 2);
        s0 += __shfl_xor(s0, 4);
        s0 += __shfl_xor(s0, 8);                       // sum over all 64 cols of row
        float scale = __builtin_amdgcn_rcpf(1.f + sqrtf(1.f + s0));
        f32x4 y = yv[r];
        y[0] *= scale; y[1] *= scale; y[2] *= scale; y[3] *= scale;
        yv[r] = y;
    }
#pragma unroll
    for (int r = 0; r < 4; ++r)
        __builtin_nontemporal_store(yv[r], (f32x4*)(ob + r * 256));
}

// ---------------- fused main: per-block z-prep + 4 MFMA steps/wave ----------------
// Load order fixes vmcnt semantics: z(16) -> bias(4) -> x step-0 (4): prep data ready
// early while x loads stay in flight across the raw barriers.
// zfl writes are packed ds_write_b64 (thread owns fragment s=kq>>1, e=half*4..+3):
// lanes spread across bank pairs -> <=2-way aliasing (free), vs 8-way scalar b16.
__global__ __launch_bounds__(256, 4) void mlr_fused_kernel(const float* __restrict__ x,
                                                           const float* __restrict__ z,
                                                           const float* __restrict__ bias,
                                                           float* __restrict__ out) {
    __shared__ float  part[4][64];
    __shared__ __bf16 zfl[4096];    // bf16 z_unit fragments, frag i: zfl[i*512 + lane*8]

    const int tid  = threadIdx.x;
    const int lane = tid & 63;
    const int lo   = lane & 15;     // A-row / C-col index
    const int hi   = lane >> 4;     // k-group / C-row-group
    const int w    = tid >> 6;
    const int o    = lane;          // prep column (== lane)
    const int kq   = w;             // prep k-quarter
    const int wv   = blockIdx.x * 4 + w;
    const size_t rowbase = (size_t)wv * 64;            // 4 steps x 16 rows

    // ---- issue loads: z first, bias, then step-0 x (stays outstanding) ----
    float zv[16];
#pragma unroll
    for (int kk = 0; kk < 16; ++kk)
        zv[kk] = z[(kq * 16 + kk) * 64 + o];           // coalesced, L2-resident

    float bb[4];
#pragma unroll
    for (int t = 0; t < 4; ++t) bb[t] = bias[4 * lo + t];

    const char* xb = (const char*)x + (rowbase + (size_t)lo) * 256 + hi * 16;
    XQuad x0 = loadx(xb);

    // ---- prep: column partial norms ----
    float n2 = 0.f;
#pragma unroll
    for (int kk = 0; kk < 16; ++kk) n2 = fmaf(zv[kk], zv[kk], n2);
    part[kq][o] = n2;
    asm volatile("s_waitcnt lgkmcnt(0)" ::: "memory");
    __builtin_amdgcn_s_barrier();

    float tot_own = part[0][o] + part[1][o] + part[2][o] + part[3][o];
    float zn_own  = fmaxf(sqrtf(tot_own), 1e-15f);
    float inv     = 1.f / zn_own;

    // per-col epilogue constants for physical cols 4lo+t, built in-register via shfl
    f32x4 cc[4];
#pragma unroll
    for (int t = 0; t < 4; ++t) {
        float tot_c = __shfl(tot_own, 4 * lo + t);
        float zn_c  = fmaxf(sqrtf(tot_c), 1e-15f);
        float e  = __builtin_amdgcn_exp2f(2.f * bb[t] * LOG2E);   // e^{2b}
        float re = __builtin_amdgcn_rcpf(e);
        cc[t] = (f32x4){e + re, 0.5f * (e - re), 2.f * zn_c, 0.f}; // {2cosh, sinh, 2zn}
    }

    // ---- z_unit bf16 fragments -> LDS, packed b64 writes ----
    // thread (kq,o): fragment s = kq>>1 fixed, e = (kq&1)*4 + j, j=0..3 contiguous;
    // byte addr = (s*4+tf)*1024 + (h2*16+cs)*16 + half*8, h2 = 0..3.
    {
        const int tf = o & 3, cs = o >> 2;
        const int s = kq >> 1, half = kq & 1;
        char* zb = (char*)zfl + (s * 4 + tf) * 1024 + cs * 16 + half * 8;
#pragma unroll
        for (int h2 = 0; h2 < 4; ++h2) {
            bf16x4 pk;
            pk[0] = (__bf16)(zv[4 * h2 + 0] * inv);
            pk[1] = (__bf16)(zv[4 * h2 + 1] * inv);
            pk[2] = (__bf16)(zv[4 * h2 + 2] * inv);
            pk[3] = (__bf16)(zv[4 * h2 + 3] * inv);
            *(bf16x4*)(zb + h2 * 256) = pk;            // ds_write_b64
        }
    }
    asm volatile("s_waitcnt lgkmcnt(0)" ::: "memory");
    __builtin_amdgcn_s_barrier();

    // ---- B fragments from LDS ----
    bf16x8 bfr[8];
#pragma unroll
    for (int i = 0; i < 8; ++i)
        bfr[i] = *(const bf16x8*)((const char*)zfl + i * 1024 + lane * 16);

    char* ob = (char*)out + (rowbase + (size_t)hi * 4) * 256 + lo * 16;

    // ---- 4 steps, straight-line; step k+1 loads issued under step-k epilogue ----
    StepMid m0 = mlr_gemm(x0, bfr);
    XQuad x1 = loadx(xb + 4096);
    mlr_fin(m0, cc, lo, hi, ob);

    StepMid m1 = mlr_gemm(x1, bfr);
    XQuad x2 = loadx(xb + 8192);
    mlr_fin(m1, cc, lo, hi, ob + 4096);

    StepMid m2 = mlr_gemm(x2, bfr);
    XQuad x3 = loadx(xb + 12288);
    mlr_fin(m2, cc, lo, hi, ob + 8192);

    StepMid m3 = mlr_gemm(x3, bfr);
    mlr_fin(m3, cc, lo, hi, ob + 12288);
}

extern "C" void kernel_launch(void* const* d_in, const int* in_sizes, int n_in,
                              void* d_out, int out_size, void* d_ws, size_t ws_size,
                              hipStream_t stream) {
    const float* x    = (const float*)d_in[0];
    const float* z    = (const float*)d_in[1];
    const float* bias = (const float*)d_in[2];
    float* out = (float*)d_out;

    mlr_fused_kernel<<<dim3(4096), dim3(256), 0, stream>>>(x, z, bias, out);
}

// Round 15
// 95.951 us; speedup vs baseline: 1.0192x; 1.0192x over previous
//
#include <hip/hip_runtime.h>
#include <math.h>

// MidpointMLR: B=1048576, F=64, c=1. Single fused kernel (prep folded in per block).
// out = proj( sinh( 2*z_norm * asinh( (2*(x@zu)*cosh(2b) - (1+cx2)*sinh(2b)) / max(1-cx2,eps) ) ) )

#define MLR_B 1048576

typedef __bf16 bf16x8 __attribute__((ext_vector_type(8)));
typedef __bf16 bf16x4 __attribute__((ext_vector_type(4)));
typedef float  f32x4  __attribute__((ext_vector_type(4)));

#define LOG2E 1.4426950408889634f

// y = sinh( g * asinh(t) ) via exp2/log2 — sign-transparent: u = t+sqrt(1+t^2) > 0.
// NB: __builtin_amdgcn_logf IS v_log_f32 = log2.
__device__ __forceinline__ float poin_y(float dot, float ch2, float sh, float g,
                                        float opc, float rden) {
    float t = fmaf(dot, ch2, -(opc * sh)) * rden;
    float u = t + sqrtf(fmaf(t, t, 1.f));
    float w = __builtin_amdgcn_exp2f(g * __builtin_amdgcn_logf(u));   // u^g
    return 0.5f * (w - __builtin_amdgcn_rcpf(w));
}

struct StepMid {
    f32x4 acc[4];
    float p;        // cx2 for row lo
};

// gemm phase: cx2 + bf16 pack + 8 MFMA. c0..c3 die here.
__device__ __forceinline__ StepMid mlr_gemm(f32x4 c0, f32x4 c1, f32x4 c2, f32x4 c3,
                                            const bf16x8* bfr) {
    StepMid m;
    float p = 0.f;
#pragma unroll
    for (int j = 0; j < 4; ++j) {
        p = fmaf(c0[j], c0[j], p); p = fmaf(c1[j], c1[j], p);
        p = fmaf(c2[j], c2[j], p); p = fmaf(c3[j], c3[j], p);
    }
    p += __shfl_xor(p, 16);
    p += __shfl_xor(p, 32);
    m.p = p;

    bf16x8 a0, a1;
#pragma unroll
    for (int j = 0; j < 4; ++j) {
        a0[j]     = (__bf16)c0[j];
        a0[4 + j] = (__bf16)c1[j];
        a1[j]     = (__bf16)c2[j];
        a1[4 + j] = (__bf16)c3[j];
    }

#pragma unroll
    for (int t = 0; t < 4; ++t) {
        m.acc[t] = (f32x4){0.f, 0.f, 0.f, 0.f};
        m.acc[t] = __builtin_amdgcn_mfma_f32_16x16x32_bf16(a0, bfr[t],     m.acc[t], 0, 0, 0);
        m.acc[t] = __builtin_amdgcn_mfma_f32_16x16x32_bf16(a1, bfr[4 + t], m.acc[t], 0, 0, 0);
    }
    return m;
}

// finish phase: transcendental epilogue + projection + nt stores.
// C/D map col=lo, row=4*hi+reg; acc[t][r] = physical col 4*lo+t.
__device__ __forceinline__ void mlr_fin(const StepMid& m, const f32x4* cc,
                                        int lo, int hi, char* ob) {
    f32x4 yv[4]; float S[4];
#pragma unroll
    for (int r = 0; r < 4; ++r) {
        float cxr  = __shfl(m.p, hi * 4 + r);          // cx2 of row 4*hi+r
        float opc  = 1.f + cxr;
        float rden = __builtin_amdgcn_rcpf(fmaxf(1.f - cxr, 1e-15f));
        float s0 = 0.f;
        f32x4 y;
#pragma unroll
        for (int t = 0; t < 4; ++t) {
            float v = poin_y(m.acc[t][r], cc[t].x, cc[t].y, cc[t].z, opc, rden);
            y[t] = v;
            s0 = fmaf(v, v, s0);
        }
        yv[r] = y;
        S[r] = s0;
    }
#pragma unroll
    for (int r = 0; r < 4; ++r) {
        float s0 = S[r];
        s0 += __shfl_xor(s0, 1);
        s0 += __shfl_xor(s0, 2);
        s0 += __shfl_xor(s0, 4);
        s0 += __shfl_xor(s0, 8);                       // sum over all 64 cols of row
        float scale = __builtin_amdgcn_rcpf(1.f + sqrtf(1.f + s0));
        f32x4 y = yv[r];
        y[0] *= scale; y[1] *= scale; y[2] *= scale; y[3] *= scale;
        yv[r] = y;
    }
#pragma unroll
    for (int r = 0; r < 4; ++r)
        __builtin_nontemporal_store(yv[r], (f32x4*)(ob + r * 256));
}

// ---------------- fused main: per-block z-prep (L2-resident) + 2 MFMA steps/wave ----
// Load order fixes vmcnt semantics: z(16) -> bias(4) -> x(4): prep data ready at
// vmcnt(4) while x loads stay in flight across the raw barriers (no vmcnt drain).
// zfl writes are packed ds_write_b64 (thread owns fragment s=kq>>1, e=(kq&1)*4..+3):
// 4 instrs/thread instead of 16 scattered ds_write_b16 (8-way bank-aliased).
__global__ __launch_bounds__(256, 4) void mlr_fused_kernel(const float* __restrict__ x,
                                                           const float* __restrict__ z,
                                                           const float* __restrict__ bias,
                                                           float* __restrict__ out) {
    __shared__ float  part[4][64];
    __shared__ __bf16 zfl[4096];    // bf16 z_unit fragments, frag i: zfl[i*512 + lane*8]

    const int tid  = threadIdx.x;
    const int lane = tid & 63;
    const int lo   = lane & 15;     // A-row / C-col index
    const int hi   = lane >> 4;     // k-group / C-row-group
    const int w    = tid >> 6;
    const int o    = lane;          // prep column (== lane)
    const int kq   = w;             // prep k-quarter
    const int wv   = blockIdx.x * 4 + w;
    const size_t rowbase = (size_t)wv * 32;            // 2 steps x 16 rows

    // ---- issue loads: z first, bias, then step-0 x (stays outstanding) ----
    float zv[16];
#pragma unroll
    for (int kk = 0; kk < 16; ++kk)
        zv[kk] = z[(kq * 16 + kk) * 64 + o];           // coalesced, L2-resident

    float bb[4];
#pragma unroll
    for (int t = 0; t < 4; ++t) bb[t] = bias[4 * lo + t];

    const char* xb = (const char*)x + (rowbase + (size_t)lo) * 256 + hi * 16;
    f32x4 c0 = *(const f32x4*)(xb + 0);
    f32x4 c1 = *(const f32x4*)(xb + 64);
    f32x4 c2 = *(const f32x4*)(xb + 128);
    f32x4 c3 = *(const f32x4*)(xb + 192);

    // ---- prep: column partial norms (needs zv only) ----
    float n2 = 0.f;
#pragma unroll
    for (int kk = 0; kk < 16; ++kk) n2 = fmaf(zv[kk], zv[kk], n2);
    part[kq][o] = n2;
    asm volatile("s_waitcnt lgkmcnt(0)" ::: "memory");
    __builtin_amdgcn_s_barrier();

    float tot_own = part[0][o] + part[1][o] + part[2][o] + part[3][o];
    float zn_own  = fmaxf(sqrtf(tot_own), 1e-15f);
    float inv     = 1.f / zn_own;

    // per-col epilogue constants for physical cols 4lo+t, built in-register via shfl
    f32x4 cc[4];
#pragma unroll
    for (int t = 0; t < 4; ++t) {
        float tot_c = __shfl(tot_own, 4 * lo + t);
        float zn_c  = fmaxf(sqrtf(tot_c), 1e-15f);
        float e  = __builtin_amdgcn_exp2f(2.f * bb[t] * LOG2E);   // e^{2b}
        float re = __builtin_amdgcn_rcpf(e);
        cc[t] = (f32x4){e + re, 0.5f * (e - re), 2.f * zn_c, 0.f}; // {2cosh, sinh, 2zn}
    }

    // ---- z_unit bf16 fragments -> LDS, packed b64 writes ----
    // thread (kq,o): fragment s = kq>>1 fixed, e = (kq&1)*4 + j, j=0..3 contiguous;
    // byte addr = (s*4+tf)*1024 + (h2*16+cs)*16 + half*8, h2 = 0..3.
    // k for slot (s,half,h2,j) = 16*(2s+half) + 4*h2 + j = kq*16 + 4*h2 + j ✓ (zv order)
    {
        const int tf = o & 3, cs = o >> 2;
        const int s = kq >> 1, half = kq & 1;
        char* zb = (char*)zfl + (s * 4 + tf) * 1024 + cs * 16 + half * 8;
#pragma unroll
        for (int h2 = 0; h2 < 4; ++h2) {
            bf16x4 pk;
            pk[0] = (__bf16)(zv[4 * h2 + 0] * inv);
            pk[1] = (__bf16)(zv[4 * h2 + 1] * inv);
            pk[2] = (__bf16)(zv[4 * h2 + 2] * inv);
            pk[3] = (__bf16)(zv[4 * h2 + 3] * inv);
            *(bf16x4*)(zb + h2 * 256) = pk;            // ds_write_b64
        }
    }
    asm volatile("s_waitcnt lgkmcnt(0)" ::: "memory");
    __builtin_amdgcn_s_barrier();

    // ---- B fragments from LDS ----
    bf16x8 bfr[8];
#pragma unroll
    for (int i = 0; i < 8; ++i)
        bfr[i] = *(const bf16x8*)((const char*)zfl + i * 1024 + lane * 16);

    char* ob = (char*)out + (rowbase + (size_t)hi * 4) * 256 + lo * 16;

    // step 0 (x already in flight since prologue)
    StepMid m0 = mlr_gemm(c0, c1, c2, c3, bfr);

    // step 1 loads: issued now, latency hidden under step-0 epilogue
    f32x4 d0 = *(const f32x4*)(xb + 4096 + 0);
    f32x4 d1 = *(const f32x4*)(xb + 4096 + 64);
    f32x4 d2 = *(const f32x4*)(xb + 4096 + 128);
    f32x4 d3 = *(const f32x4*)(xb + 4096 + 192);

    mlr_fin(m0, cc, lo, hi, ob);

    StepMid m1 = mlr_gemm(d0, d1, d2, d3, bfr);
    mlr_fin(m1, cc, lo, hi, ob + 4096);
}

extern "C" void kernel_launch(void* const* d_in, const int* in_sizes, int n_in,
                              void* d_out, int out_size, void* d_ws, size_t ws_size,
                              hipStream_t stream) {
    const float* x    = (const float*)d_in[0];
    const float* z    = (const float*)d_in[1];
    const float* bias = (const float*)d_in[2];
    float* out = (float*)d_out;

    mlr_fused_kernel<<<dim3(8192), dim3(256), 0, stream>>>(x, z, bias, out);
}